// Round 6
// baseline (246.192 us; speedup 1.0000x reference)
//
#include <hip/hip_runtime.h>

// LinearImputer: linear interp over zero runs along time axis (B=32,T=4096,D=256 f32).
// Semantics (match JAX ref):
//   prev = last valid <= t (-1 if none); nxt = first valid >= t (T if none)
//   interior = !valid && prev>=0 && nxt<T
//   denom = max(nxt-prev-2, 1); pos = t-prev-1; out = x[prev] + (x[nxt]-x[prev])*pos/denom
// Boundary-touching runs stay zero.
//
// R6 = R3 base (best measured: 54.5us, 44 VGPR, quadratic in-chunk next-scan)
// with exactly two deltas:
//   (1) W 4->5: per-column fallback prob 0.3^5->0.3^6 (waves hitting the serial
//       dependent-load walk: ~70% -> ~31%); halo loads still issued with main loads.
//   (2) fallback walk batched 2 rows/iter (both loads in flight before use ->
//       half the dependent-chain depth for affected waves).
// R4/R5 lesson: suffix-array & packing variants conserve op count and cost
// registers; emit stays the R3 quadratic form (compiler shares the v_cmp masks).

typedef float f32x4 __attribute__((ext_vector_type(4)));

constexpr int B = 32, T = 4096, D = 256;
constexpr int L = 8;        // rows per thread
constexpr int W = 5;        // halo rows prefetched per side
constexpr int NC = T / L;   // 512
constexpr int C4 = D / 4;   // 64

__global__ __launch_bounds__(256, 8)
void LinearImputer_kernel(const float* __restrict__ x, float* __restrict__ out) {
    const int g  = blockIdx.x * 256 + threadIdx.x;
    const int l  = g & (C4 - 1);        // float4 column group
    const int bc = g >> 6;
    const int c  = bc & (NC - 1);       // chunk index (wave-uniform)
    const int b  = bc >> 9;
    const int t0 = c * L;
    const int t1 = t0 + L;

    const f32x4* __restrict__ x4 = (const f32x4*)x;
    f32x4* __restrict__       o4 = (f32x4*)out;
    const size_t base = ((size_t)b * T) * C4 + l;

    const bool hasB = (c > 0);          // wave-uniform
    const bool hasF = (c < NC - 1);

    // ---- issue ALL loads up-front: 8 main + 5 back-halo + 5 fwd-halo ----
    f32x4 hb4[W], hf4[W];
    if (hasB) {
        #pragma unroll
        for (int w = 0; w < W; ++w) hb4[w] = x4[base + (size_t)(t0 - 1 - w) * C4];
    }
    if (hasF) {
        #pragma unroll
        for (int w = 0; w < W; ++w) hf4[w] = x4[base + (size_t)(t1 + w) * C4];
    }
    float v[L][4];
    #pragma unroll
    for (int j = 0; j < L; ++j) {
        f32x4 tv = x4[base + (size_t)(t0 + j) * C4];
        v[j][0] = tv.x; v[j][1] = tv.y; v[j][2] = tv.z; v[j][3] = tv.w;
    }

    // ---- backward halo -> prev carry (pi,pv) ----
    int pi[4]; float pv[4];
    #pragma unroll
    for (int cc = 0; cc < 4; ++cc) { pi[cc] = -1; pv[cc] = 0.0f; }
    if (hasB) {
        #pragma unroll
        for (int w = 0; w < W; ++w) {
            float h[4] = {hb4[w].x, hb4[w].y, hb4[w].z, hb4[w].w};
            #pragma unroll
            for (int cc = 0; cc < 4; ++cc)
                if (pi[cc] < 0 && h[cc] != 0.0f) { pi[cc] = t0 - 1 - w; pv[cc] = h[cc]; }
        }
        // rare deep-run fallback (per-column prob 0.3^6 ~ 0.07%), 2 rows/iter
        int pending = 0;
        #pragma unroll
        for (int cc = 0; cc < 4; ++cc)
            if (v[0][cc] == 0.0f && pi[cc] < 0) pending |= (1 << cc);
        if (pending) {
            int tt = t0 - 1 - W;
            while (pending && tt >= 0) {
                f32x4 a0 = x4[base + (size_t)tt * C4];
                const bool has2 = (tt - 1) >= 0;
                f32x4 a1;
                if (has2) a1 = x4[base + (size_t)(tt - 1) * C4];
                float h0[4] = {a0.x, a0.y, a0.z, a0.w};
                #pragma unroll
                for (int cc = 0; cc < 4; ++cc)
                    if (((pending >> cc) & 1) && h0[cc] != 0.0f) {
                        pi[cc] = tt; pv[cc] = h0[cc]; pending &= ~(1 << cc);
                    }
                if (has2 && pending) {
                    float h1[4] = {a1.x, a1.y, a1.z, a1.w};
                    #pragma unroll
                    for (int cc = 0; cc < 4; ++cc)
                        if (((pending >> cc) & 1) && h1[cc] != 0.0f) {
                            pi[cc] = tt - 1; pv[cc] = h1[cc]; pending &= ~(1 << cc);
                        }
                }
                tt -= 2;
            }
        }
    }

    // ---- forward halo -> next seed (ni,nv) ----
    int ni[4]; float nv[4];
    #pragma unroll
    for (int cc = 0; cc < 4; ++cc) { ni[cc] = T; nv[cc] = 0.0f; }
    if (hasF) {
        #pragma unroll
        for (int w = 0; w < W; ++w) {
            float h[4] = {hf4[w].x, hf4[w].y, hf4[w].z, hf4[w].w};
            #pragma unroll
            for (int cc = 0; cc < 4; ++cc)
                if (ni[cc] == T && h[cc] != 0.0f) { ni[cc] = t1 + w; nv[cc] = h[cc]; }
        }
        int pending = 0;
        #pragma unroll
        for (int cc = 0; cc < 4; ++cc)
            if (v[L - 1][cc] == 0.0f && ni[cc] == T) pending |= (1 << cc);
        if (pending) {
            int tt = t1 + W;
            while (pending && tt < T) {
                f32x4 a0 = x4[base + (size_t)tt * C4];
                const bool has2 = (tt + 1) < T;
                f32x4 a1;
                if (has2) a1 = x4[base + (size_t)(tt + 1) * C4];
                float h0[4] = {a0.x, a0.y, a0.z, a0.w};
                #pragma unroll
                for (int cc = 0; cc < 4; ++cc)
                    if (((pending >> cc) & 1) && h0[cc] != 0.0f) {
                        ni[cc] = tt; nv[cc] = h0[cc]; pending &= ~(1 << cc);
                    }
                if (has2 && pending) {
                    float h1[4] = {a1.x, a1.y, a1.z, a1.w};
                    #pragma unroll
                    for (int cc = 0; cc < 4; ++cc)
                        if (((pending >> cc) & 1) && h1[cc] != 0.0f) {
                            ni[cc] = tt + 1; nv[cc] = h1[cc]; pending &= ~(1 << cc);
                        }
                }
                tt += 2;
            }
        }
    }

    // ---- forward emit: prev-carry + unrolled in-chunk next-scan (R3 form) ----
    #pragma unroll
    for (int j = 0; j < L; ++j) {
        float o[4];
        #pragma unroll
        for (int cc = 0; cc < 4; ++cc) {
            float val = v[j][cc];
            if (val != 0.0f) {
                o[cc] = val; pi[cc] = t0 + j; pv[cc] = val;
            } else {
                // nearest in-chunk next wins (reverse unroll), else halo next
                int nxi = ni[cc]; float nxv = nv[cc];
                #pragma unroll
                for (int k = L - 1; k > j; --k)
                    if (v[k][cc] != 0.0f) { nxi = t0 + k; nxv = v[k][cc]; }
                if (pi[cc] >= 0 && nxi < T) {
                    int denom = nxi - pi[cc] - 2;        // run_len - 1
                    if (denom < 1) denom = 1;
                    float frac = __fdividef((float)(t0 + j - pi[cc] - 1), (float)denom);
                    o[cc] = pv[cc] + (nxv - pv[cc]) * frac;
                } else {
                    o[cc] = 0.0f;                        // boundary-touching run
                }
            }
        }
        f32x4 ov; ov.x = o[0]; ov.y = o[1]; ov.z = o[2]; ov.w = o[3];
        __builtin_nontemporal_store(ov, &o4[base + (size_t)(t0 + j) * C4]);
    }
}

extern "C" void kernel_launch(void* const* d_in, const int* in_sizes, int n_in,
                              void* d_out, int out_size, void* d_ws, size_t ws_size,
                              hipStream_t stream) {
    const float* x = (const float*)d_in[0];
    float* out = (float*)d_out;
    const int total_threads = B * NC * C4;   // 1,048,576
    dim3 grid(total_threads / 256), block(256);
    LinearImputer_kernel<<<grid, block, 0, stream>>>(x, out);
}

// Round 7
// 54.098 us; speedup vs baseline: 4.5509x; 4.5509x over previous
//
#include <hip/hip_runtime.h>

// LinearImputer: linear interp over zero runs along time axis (B=32,T=4096,D=256 f32).
// Semantics (match JAX ref):
//   prev = last valid <= t (-1 if none); nxt = first valid >= t (T if none)
//   interior = !valid && prev>=0 && nxt<T
//   denom = max(nxt-prev-2, 1); pos = t-prev-1; out = x[prev] + (x[nxt]-x[prev])*pos/denom
// Boundary-touching runs stay zero.
//
// R7 = R6 minus the launch_bounds min-waves pin. R6 lesson: __launch_bounds__(256,8)
// capped VGPR at 32 -> the 18-deep up-front load burst (72 VGPR of destinations)
// serialized -> 246us at 81% occupancy. ILP (loads in flight) beats occupancy here.
// Deltas vs R3 base (54.5us): W 4->5 halo, fallback walk batched 2 rows/iter.

typedef float f32x4 __attribute__((ext_vector_type(4)));

constexpr int B = 32, T = 4096, D = 256;
constexpr int L = 8;        // rows per thread
constexpr int W = 5;        // halo rows prefetched per side
constexpr int NC = T / L;   // 512
constexpr int C4 = D / 4;   // 64

__global__ __launch_bounds__(256)
void LinearImputer_kernel(const float* __restrict__ x, float* __restrict__ out) {
    const int g  = blockIdx.x * 256 + threadIdx.x;
    const int l  = g & (C4 - 1);        // float4 column group
    const int bc = g >> 6;
    const int c  = bc & (NC - 1);       // chunk index (wave-uniform)
    const int b  = bc >> 9;
    const int t0 = c * L;
    const int t1 = t0 + L;

    const f32x4* __restrict__ x4 = (const f32x4*)x;
    f32x4* __restrict__       o4 = (f32x4*)out;
    const size_t base = ((size_t)b * T) * C4 + l;

    const bool hasB = (c > 0);          // wave-uniform
    const bool hasF = (c < NC - 1);

    // ---- issue ALL loads up-front: 8 main + 5 back-halo + 5 fwd-halo ----
    f32x4 hb4[W], hf4[W];
    if (hasB) {
        #pragma unroll
        for (int w = 0; w < W; ++w) hb4[w] = x4[base + (size_t)(t0 - 1 - w) * C4];
    }
    if (hasF) {
        #pragma unroll
        for (int w = 0; w < W; ++w) hf4[w] = x4[base + (size_t)(t1 + w) * C4];
    }
    float v[L][4];
    #pragma unroll
    for (int j = 0; j < L; ++j) {
        f32x4 tv = x4[base + (size_t)(t0 + j) * C4];
        v[j][0] = tv.x; v[j][1] = tv.y; v[j][2] = tv.z; v[j][3] = tv.w;
    }

    // ---- backward halo -> prev carry (pi,pv) ----
    int pi[4]; float pv[4];
    #pragma unroll
    for (int cc = 0; cc < 4; ++cc) { pi[cc] = -1; pv[cc] = 0.0f; }
    if (hasB) {
        #pragma unroll
        for (int w = 0; w < W; ++w) {
            float h[4] = {hb4[w].x, hb4[w].y, hb4[w].z, hb4[w].w};
            #pragma unroll
            for (int cc = 0; cc < 4; ++cc)
                if (pi[cc] < 0 && h[cc] != 0.0f) { pi[cc] = t0 - 1 - w; pv[cc] = h[cc]; }
        }
        // rare deep-run fallback (per-column prob 0.3^6 ~ 0.07%), 2 rows/iter
        int pending = 0;
        #pragma unroll
        for (int cc = 0; cc < 4; ++cc)
            if (v[0][cc] == 0.0f && pi[cc] < 0) pending |= (1 << cc);
        if (pending) {
            int tt = t0 - 1 - W;
            while (pending && tt >= 0) {
                f32x4 a0 = x4[base + (size_t)tt * C4];
                const bool has2 = (tt - 1) >= 0;
                f32x4 a1;
                if (has2) a1 = x4[base + (size_t)(tt - 1) * C4];
                float h0[4] = {a0.x, a0.y, a0.z, a0.w};
                #pragma unroll
                for (int cc = 0; cc < 4; ++cc)
                    if (((pending >> cc) & 1) && h0[cc] != 0.0f) {
                        pi[cc] = tt; pv[cc] = h0[cc]; pending &= ~(1 << cc);
                    }
                if (has2 && pending) {
                    float h1[4] = {a1.x, a1.y, a1.z, a1.w};
                    #pragma unroll
                    for (int cc = 0; cc < 4; ++cc)
                        if (((pending >> cc) & 1) && h1[cc] != 0.0f) {
                            pi[cc] = tt - 1; pv[cc] = h1[cc]; pending &= ~(1 << cc);
                        }
                }
                tt -= 2;
            }
        }
    }

    // ---- forward halo -> next seed (ni,nv) ----
    int ni[4]; float nv[4];
    #pragma unroll
    for (int cc = 0; cc < 4; ++cc) { ni[cc] = T; nv[cc] = 0.0f; }
    if (hasF) {
        #pragma unroll
        for (int w = 0; w < W; ++w) {
            float h[4] = {hf4[w].x, hf4[w].y, hf4[w].z, hf4[w].w};
            #pragma unroll
            for (int cc = 0; cc < 4; ++cc)
                if (ni[cc] == T && h[cc] != 0.0f) { ni[cc] = t1 + w; nv[cc] = h[cc]; }
        }
        int pending = 0;
        #pragma unroll
        for (int cc = 0; cc < 4; ++cc)
            if (v[L - 1][cc] == 0.0f && ni[cc] == T) pending |= (1 << cc);
        if (pending) {
            int tt = t1 + W;
            while (pending && tt < T) {
                f32x4 a0 = x4[base + (size_t)tt * C4];
                const bool has2 = (tt + 1) < T;
                f32x4 a1;
                if (has2) a1 = x4[base + (size_t)(tt + 1) * C4];
                float h0[4] = {a0.x, a0.y, a0.z, a0.w};
                #pragma unroll
                for (int cc = 0; cc < 4; ++cc)
                    if (((pending >> cc) & 1) && h0[cc] != 0.0f) {
                        ni[cc] = tt; nv[cc] = h0[cc]; pending &= ~(1 << cc);
                    }
                if (has2 && pending) {
                    float h1[4] = {a1.x, a1.y, a1.z, a1.w};
                    #pragma unroll
                    for (int cc = 0; cc < 4; ++cc)
                        if (((pending >> cc) & 1) && h1[cc] != 0.0f) {
                            ni[cc] = tt + 1; nv[cc] = h1[cc]; pending &= ~(1 << cc);
                        }
                }
                tt += 2;
            }
        }
    }

    // ---- forward emit: prev-carry + unrolled in-chunk next-scan (R3 form) ----
    #pragma unroll
    for (int j = 0; j < L; ++j) {
        float o[4];
        #pragma unroll
        for (int cc = 0; cc < 4; ++cc) {
            float val = v[j][cc];
            if (val != 0.0f) {
                o[cc] = val; pi[cc] = t0 + j; pv[cc] = val;
            } else {
                // nearest in-chunk next wins (reverse unroll), else halo next
                int nxi = ni[cc]; float nxv = nv[cc];
                #pragma unroll
                for (int k = L - 1; k > j; --k)
                    if (v[k][cc] != 0.0f) { nxi = t0 + k; nxv = v[k][cc]; }
                if (pi[cc] >= 0 && nxi < T) {
                    int denom = nxi - pi[cc] - 2;        // run_len - 1
                    if (denom < 1) denom = 1;
                    float frac = __fdividef((float)(t0 + j - pi[cc] - 1), (float)denom);
                    o[cc] = pv[cc] + (nxv - pv[cc]) * frac;
                } else {
                    o[cc] = 0.0f;                        // boundary-touching run
                }
            }
        }
        f32x4 ov; ov.x = o[0]; ov.y = o[1]; ov.z = o[2]; ov.w = o[3];
        __builtin_nontemporal_store(ov, &o4[base + (size_t)(t0 + j) * C4]);
    }
}

extern "C" void kernel_launch(void* const* d_in, const int* in_sizes, int n_in,
                              void* d_out, int out_size, void* d_ws, size_t ws_size,
                              hipStream_t stream) {
    const float* x = (const float*)d_in[0];
    float* out = (float*)d_out;
    const int total_threads = B * NC * C4;   // 1,048,576
    dim3 grid(total_threads / 256), block(256);
    LinearImputer_kernel<<<grid, block, 0, stream>>>(x, out);
}